// Round 2
// baseline (34919.864 us; speedup 1.0000x reference)
//
#include <hip/hip_runtime.h>

#define NVOX (128*128*128)
#define NK 45
#define NSL 48
#define NPIX (NSL*128*128)

// ---------------------------------------------------------------------------
// trilinear gather with reference semantics (out-of-bounds corners contribute 0)
__device__ __forceinline__ float trilerp_gather(const float* __restrict__ v,
                                                float x, float y, float z)
{
    float x0f = floorf(x), y0f = floorf(y), z0f = floorf(z);
    int x0 = (int)x0f, y0 = (int)y0f, z0 = (int)z0f;
    float fx = x - x0f, fy = y - y0f, fz = z - z0f;

    if (((unsigned)x0 < 127u) & ((unsigned)y0 < 127u) & ((unsigned)z0 < 127u)) {
        const float* p = v + z0*16384 + y0*128 + x0;
        float v000 = p[0],     v001 = p[1];
        float v010 = p[128],   v011 = p[129];
        float v100 = p[16384], v101 = p[16385];
        float v110 = p[16512], v111 = p[16513];
        float c00 = v000 + fx*(v001 - v000);
        float c01 = v010 + fx*(v011 - v010);
        float c10 = v100 + fx*(v101 - v100);
        float c11 = v110 + fx*(v111 - v110);
        float c0  = c00 + fy*(c01 - c00);
        float c1  = c10 + fy*(c11 - c10);
        return c0 + fz*(c1 - c0);
    }
    if (x0 < -1 || x0 > 127 || y0 < -1 || y0 > 127 || z0 < -1 || z0 > 127)
        return 0.f;
    float acc = 0.f;
#pragma unroll
    for (int dz = 0; dz < 2; ++dz) {
        int zi = z0 + dz;
        if ((unsigned)zi >= 128u) continue;
        float wz = dz ? fz : 1.f - fz;
#pragma unroll
        for (int dy = 0; dy < 2; ++dy) {
            int yi = y0 + dy;
            if ((unsigned)yi >= 128u) continue;
            float wy = dy ? fy : 1.f - fy;
#pragma unroll
            for (int dx = 0; dx < 2; ++dx) {
                int xi = x0 + dx;
                if ((unsigned)xi >= 128u) continue;
                float wx = dx ? fx : 1.f - fx;
                acc += wz*wy*wx * v[zi*16384 + yi*128 + xi];
            }
        }
    }
    return acc;
}

__device__ __forceinline__ void trilerp_splat(float* __restrict__ v,
                                              float x, float y, float z, float val)
{
    float x0f = floorf(x), y0f = floorf(y), z0f = floorf(z);
    int x0 = (int)x0f, y0 = (int)y0f, z0 = (int)z0f;
    float fx = x - x0f, fy = y - y0f, fz = z - z0f;

    if (((unsigned)x0 < 127u) & ((unsigned)y0 < 127u) & ((unsigned)z0 < 127u)) {
        float* p = v + z0*16384 + y0*128 + x0;
        float wx1 = fx, wx0 = 1.f - fx;
        float wy1 = fy, wy0 = 1.f - fy;
        float wz1 = fz, wz0 = 1.f - fz;
        unsafeAtomicAdd(p,         val*wz0*wy0*wx0);
        unsafeAtomicAdd(p+1,       val*wz0*wy0*wx1);
        unsafeAtomicAdd(p+128,     val*wz0*wy1*wx0);
        unsafeAtomicAdd(p+129,     val*wz0*wy1*wx1);
        unsafeAtomicAdd(p+16384,   val*wz1*wy0*wx0);
        unsafeAtomicAdd(p+16385,   val*wz1*wy0*wx1);
        unsafeAtomicAdd(p+16512,   val*wz1*wy1*wx0);
        unsafeAtomicAdd(p+16513,   val*wz1*wy1*wx1);
        return;
    }
    if (x0 < -1 || x0 > 127 || y0 < -1 || y0 > 127 || z0 < -1 || z0 > 127)
        return;
#pragma unroll
    for (int dz = 0; dz < 2; ++dz) {
        int zi = z0 + dz;
        if ((unsigned)zi >= 128u) continue;
        float wz = dz ? fz : 1.f - fz;
#pragma unroll
        for (int dy = 0; dy < 2; ++dy) {
            int yi = y0 + dy;
            if ((unsigned)yi >= 128u) continue;
            float wy = dy ? fy : 1.f - fy;
#pragma unroll
            for (int dx = 0; dx < 2; ++dx) {
                int xi = x0 + dx;
                if ((unsigned)xi >= 128u) continue;
                float wx = dx ? fx : 1.f - fx;
                unsafeAtomicAdd(v + zi*16384 + yi*128 + xi, val*wz*wy*wx);
            }
        }
    }
}

// ---------------------------------------------------------------------------
// precompute shift[n][k] = R_n @ off_k + t_n + center  (48*45*3 floats)
__global__ void k_shifts(const float* __restrict__ trans, float* __restrict__ shifts)
{
    int i = blockIdx.x * blockDim.x + threadIdx.x;
    if (i >= NSL * NK) return;
    int n = i / NK, k = i % NK;
    int kz = k / 9, ky = (k % 9) / 3, kx = k % 3;
    float ox = (float)(kx - 1);
    float oy = (float)(ky - 1);
    float oz = (float)(kz - 2);
    const float* T = trans + n * 12;
    shifts[i*3+0] = T[0]*ox + T[1]*oy + T[2]*oz  + T[3]  + 63.5f;
    shifts[i*3+1] = T[4]*ox + T[5]*oy + T[6]*oz  + T[7]  + 63.5f;
    shifts[i*3+2] = T[8]*ox + T[9]*oy + T[10]*oz + T[11] + 63.5f;
}

// ---------------------------------------------------------------------------
// fused AtA: per pixel gather s = sum_k w_k * trilerp(p, pt_k) then splat w_k*s
__global__ __launch_bounds__(256) void k_ata(const float* __restrict__ pin,
                                             float* __restrict__ pout,
                                             const float* __restrict__ shifts,
                                             const float* __restrict__ psf,
                                             const float* __restrict__ trans)
{
    __shared__ float sh[NK*4];            // [k*3+i] shifts, [135+k] weights
    int n   = blockIdx.x >> 6;
    int tid = threadIdx.x;
    if (tid < NK*3) sh[tid] = shifts[n*NK*3 + tid];
    if (tid >= 192 && tid < 192 + NK) sh[NK*3 + (tid - 192)] = psf[tid - 192];
    const float* T = trans + n * 12;
    float R00 = T[0], R01 = T[1], R10 = T[4], R11 = T[5], R20 = T[8], R21 = T[9];
    __syncthreads();

    int idx = (blockIdx.x & 63) * 256 + tid;
    int h = idx >> 7, w = idx & 127;
    float bx = ((float)w - 63.5f) * 1.25f;
    float by = ((float)h - 63.5f) * 1.25f;
    float rbx = R00*bx + R01*by;
    float rby = R10*bx + R11*by;
    float rbz = R20*bx + R21*by;

    float s = 0.f;
#pragma unroll 1
    for (int k = 0; k < NK; ++k)
        s += sh[NK*3+k] * trilerp_gather(pin, rbx + sh[k*3], rby + sh[k*3+1], rbz + sh[k*3+2]);

#pragma unroll 1
    for (int k = 0; k < NK; ++k)
        trilerp_splat(pout, rbx + sh[k*3], rby + sh[k*3+1], rbz + sh[k*3+2], sh[NK*3+k] * s);
}

// At only (for b = At(y))
__global__ __launch_bounds__(256) void k_at(const float* __restrict__ y,
                                            float* __restrict__ pout,
                                            const float* __restrict__ shifts,
                                            const float* __restrict__ psf,
                                            const float* __restrict__ trans)
{
    __shared__ float sh[NK*4];
    int n   = blockIdx.x >> 6;
    int tid = threadIdx.x;
    if (tid < NK*3) sh[tid] = shifts[n*NK*3 + tid];
    if (tid >= 192 && tid < 192 + NK) sh[NK*3 + (tid - 192)] = psf[tid - 192];
    const float* T = trans + n * 12;
    float R00 = T[0], R01 = T[1], R10 = T[4], R11 = T[5], R20 = T[8], R21 = T[9];
    __syncthreads();

    int idx = (blockIdx.x & 63) * 256 + tid;
    int h = idx >> 7, w = idx & 127;
    float bx = ((float)w - 63.5f) * 1.25f;
    float by = ((float)h - 63.5f) * 1.25f;
    float rbx = R00*bx + R01*by;
    float rby = R10*bx + R11*by;
    float rbz = R20*bx + R21*by;

    float val = y[n * 16384 + idx];
#pragma unroll 1
    for (int k = 0; k < NK; ++k)
        trilerp_splat(pout, rbx + sh[k*3], rby + sh[k*3+1], rbz + sh[k*3+2], sh[NK*3+k] * val);
}

// ---------------------------------------------------------------------------
// reductions / CG vector updates
__device__ __forceinline__ void block_reduce_add(double s, double* out)
{
    for (int o = 32; o > 0; o >>= 1) s += __shfl_down(s, o);
    __shared__ double ls[4];
    int lane = threadIdx.x & 63, wid = threadIdx.x >> 6;
    if (lane == 0) ls[wid] = s;
    __syncthreads();
    if (threadIdx.x == 0) atomicAdd(out, ls[0] + ls[1] + ls[2] + ls[3]);
}

__global__ __launch_bounds__(256) void k_init(const float* __restrict__ b,
                                              const float* __restrict__ Ax,
                                              float* __restrict__ r,
                                              float* __restrict__ p,
                                              double* rr0)
{
    double s = 0.0;
    for (int i = blockIdx.x * blockDim.x + threadIdx.x; i < NVOX;
         i += gridDim.x * blockDim.x) {
        float rv = b[i] - Ax[i];
        r[i] = rv;
        p[i] = rv;
        s += (double)rv * (double)rv;
    }
    block_reduce_add(s, rr0);
}

__global__ __launch_bounds__(256) void k_dot(const float* __restrict__ a,
                                             const float* __restrict__ b,
                                             double* out)
{
    double s = 0.0;
    for (int i = blockIdx.x * blockDim.x + threadIdx.x; i < NVOX;
         i += gridDim.x * blockDim.x)
        s += (double)a[i] * (double)b[i];
    block_reduce_add(s, out);
}

__global__ __launch_bounds__(256) void k_update_xr(float* __restrict__ x,
                                                   float* __restrict__ r,
                                                   const float* __restrict__ p,
                                                   const float* __restrict__ Ap,
                                                   const double* rr, const double* pap,
                                                   double* rrn, int do_r)
{
    float alpha = (float)(rr[0] / pap[0]);
    double s = 0.0;
    for (int i = blockIdx.x * blockDim.x + threadIdx.x; i < NVOX;
         i += gridDim.x * blockDim.x) {
        x[i] += alpha * p[i];
        if (do_r) {
            float rn = r[i] - alpha * Ap[i];
            r[i] = rn;
            s += (double)rn * (double)rn;
        }
    }
    block_reduce_add(s, rrn);
}

__global__ __launch_bounds__(256) void k_update_p(float* __restrict__ p,
                                                  const float* __restrict__ r,
                                                  const double* rrn, const double* rro)
{
    float beta = (float)(rrn[0] / rro[0]);
    for (int i = blockIdx.x * blockDim.x + threadIdx.x; i < NVOX;
         i += gridDim.x * blockDim.x)
        p[i] = r[i] + beta * p[i];
}

__global__ __launch_bounds__(256) void k_relu(const float* __restrict__ x,
                                              float* __restrict__ out)
{
    for (int i = blockIdx.x * blockDim.x + threadIdx.x; i < NVOX;
         i += gridDim.x * blockDim.x)
        out[i] = fmaxf(x[i], 0.f);
}

// ---------------------------------------------------------------------------
extern "C" void kernel_launch(void* const* d_in, const int* in_sizes, int n_in,
                              void* d_out, int out_size, void* d_ws, size_t ws_size,
                              hipStream_t stream)
{
    const float* vol    = (const float*)d_in[0];   // 128^3
    const float* slices = (const float*)d_in[1];   // 48*128*128
    const float* trans  = (const float*)d_in[2];   // 48*3*4
    const float* psf    = (const float*)d_in[3];   // 45
    float* out = (float*)d_out;

    char* w = (char*)d_ws;
    float* x      = (float*)(w);
    float* b      = (float*)(w + (size_t)NVOX * 4);
    float* r      = (float*)(w + (size_t)NVOX * 8);
    float* p      = (float*)(w + (size_t)NVOX * 12);
    float* Ap     = (float*)(w + (size_t)NVOX * 16);
    float* shifts = (float*)(w + (size_t)NVOX * 20);              // 48*45*3*4 = 25920 B
    double* sc    = (double*)(w + (size_t)NVOX * 20 + 32768);     // past shifts (was the bug)
    // sc[0..10] = rr_i, sc[11..20] = pAp_i

    hipMemsetAsync(sc, 0, 21 * sizeof(double), stream);
    hipLaunchKernelGGL(k_shifts, dim3(9), dim3(256), 0, stream, trans, shifts);

    // b = At(y)
    hipMemsetAsync(b, 0, (size_t)NVOX * 4, stream);
    hipLaunchKernelGGL(k_at, dim3(NSL * 64), dim3(256), 0, stream,
                       slices, b, shifts, psf, trans);

    // x = vol (initial guess)
    hipMemcpyAsync(x, vol, (size_t)NVOX * 4, hipMemcpyDeviceToDevice, stream);

    // Ax = AtA(x)
    hipMemsetAsync(Ap, 0, (size_t)NVOX * 4, stream);
    hipLaunchKernelGGL(k_ata, dim3(NSL * 64), dim3(256), 0, stream,
                       x, Ap, shifts, psf, trans);

    // r = b - Ax; p = r; rr0 = <r,r>
    hipLaunchKernelGGL(k_init, dim3(512), dim3(256), 0, stream, b, Ap, r, p, sc + 0);

    for (int i = 0; i < 10; ++i) {
        hipMemsetAsync(Ap, 0, (size_t)NVOX * 4, stream);
        hipLaunchKernelGGL(k_ata, dim3(NSL * 64), dim3(256), 0, stream,
                           p, Ap, shifts, psf, trans);
        hipLaunchKernelGGL(k_dot, dim3(512), dim3(256), 0, stream, p, Ap, sc + 11 + i);
        hipLaunchKernelGGL(k_update_xr, dim3(512), dim3(256), 0, stream,
                           x, r, p, Ap, sc + i, sc + 11 + i, sc + i + 1, (int)(i < 9));
        if (i < 9)
            hipLaunchKernelGGL(k_update_p, dim3(512), dim3(256), 0, stream,
                               p, r, sc + i + 1, sc + i);
    }

    hipLaunchKernelGGL(k_relu, dim3(512), dim3(256), 0, stream, x, out);
}